// Round 15
// baseline (83.584 us; speedup 1.0000x reference)
//
#include <hip/hip_runtime.h>

#define N_PIX   65536
#define N_GAUSS 2048

typedef __bf16 bf16x8 __attribute__((ext_vector_type(8)));
typedef float  f32x4  __attribute__((ext_vector_type(4)));

union BF8U { uint4 u; bf16x8 h; };
__device__ inline bf16x8 as_bf(uint4 u) { BF8U x; x.u = u; return x.h; }

__device__ inline unsigned short bfbits(float f) {
  __bf16 h = (__bf16)f;
  return __builtin_bit_cast(unsigned short, h);
}
__device__ inline float bf2f(unsigned short b) {
  return (float)__builtin_bit_cast(__bf16, b);
}
__device__ inline unsigned pkb(unsigned short a, unsigned short b) {
  return (unsigned)a | ((unsigned)b << 16);
}
__device__ inline unsigned pk2f(float a, float b) {
  return pkb(bfbits(a), bfbits(b));
}

// ---------------------------------------------------------------------------
// q-MFMA K-layout (shared by P and G, K=32, 24 used):
//   k0-5 : Ghi*Phi   k6-11: Glo*Phi   k12-17: Ghi*Plo   k18-23: Glo*Plo
// Coefs include -0.5*log2(e) so w = exp2(q) == exp(-0.5*maha).
//
// PV has NO transpose (pi-reorder, r12-proven): swapped q-MFMA leaves lane
// (pix=c, grp) holding w for gauss {4grp+0..3} (q0) and {16+4grp+0..3} (q1);
// packed {q0[0],q0[1]},{q0[2],q0[3]},{q1[0],q1[1]},{q1[2],q1[3]} it is a
// valid PV B-operand under pi(grp*8+j) = (j<4) ? 4grp+j : 16+4grp+(j-4).
// prep packs the cols A-operand (row=rgb) with gauss pi(k); rgb rows 3..15
// zero => only grp==0 lanes carry output.
//
// This round: 8 waves/SIMD retest WITHOUT spill (r10's confound).
// global_load_lds staging (zero staging VGPRs), per-step cf loads (no
// 32-reg hoist), gauss 2-way split for 4 blocks/CU residency.
//
// ws layout: [0, 8192)   uint4 : GQ frags, 128 tiles x 64 lanes x 16B (A-op)
//            [8192,12288) uint4 : PVC frags (pi-ordered cols A-op), 64 tiles
// ---------------------------------------------------------------------------

__global__ __launch_bounds__(256) void prep_kernel(
    const float* __restrict__ mus, const float* __restrict__ covs,
    const float* __restrict__ cols, uint4* __restrict__ ws) {
  int tid = blockIdx.x * 256 + threadIdx.x;
  if (tid < 8192) {
    // GQ fragment: A-operand of q-MFMA. lane row = gauss (lane&15),
    // k = (lane>>4)*8 + j.  G row = [Chi0-5, Clo0-5, Chi0-5, Clo0-5, 0...]
    int lane = tid & 63;
    int tile = tid >> 6;
    int grp  = lane >> 4;
    int g    = tile * 16 + (lane & 15);
    float c00 = covs[4*g+0], c01 = covs[4*g+1];
    float c10 = covs[4*g+2], c11 = covs[4*g+3];
    float inv_det = 1.0f / (c00*c11 - c01*c10);
    float ia =  c11 * inv_det;
    float ib = -c01 * inv_det;
    float ic =  c00 * inv_det;
    float mx = mus[2*g+0], my = mus[2*g+1];
    const float kk = -0.7213475204444817f;   // -0.5*log2(e)
    float coef[6];
    coef[0] = kk * ia;
    coef[1] = kk * 2.0f * ib;
    coef[2] = kk * ic;
    coef[3] = -2.0f * kk * (ia*mx + ib*my);
    coef[4] = -2.0f * kk * (ib*mx + ic*my);
    coef[5] = kk * (ia*mx*mx + 2.0f*ib*mx*my + ic*my*my);
    unsigned short ch[6], cl[6];
    #pragma unroll
    for (int i = 0; i < 6; ++i) {
      ch[i] = bfbits(coef[i]);
      cl[i] = bfbits(coef[i] - bf2f(ch[i]));
    }
    uint4 v = make_uint4(0,0,0,0);
    if (grp == 0)      v = make_uint4(pkb(ch[0],ch[1]), pkb(ch[2],ch[3]), pkb(ch[4],ch[5]), pkb(cl[0],cl[1]));
    else if (grp == 1) v = make_uint4(pkb(cl[2],cl[3]), pkb(cl[4],cl[5]), pkb(ch[0],ch[1]), pkb(ch[2],ch[3]));
    else if (grp == 2) v = make_uint4(pkb(ch[4],ch[5]), pkb(cl[0],cl[1]), pkb(cl[2],cl[3]), pkb(cl[4],cl[5]));
    ws[tid] = v;
  } else if (tid < 12288) {
    // PVC fragment: A-operand of PV MFMA. lane row = rgb (lane&15, 3 used),
    // k = (lane>>4)*8 + j, gauss id at k-slot = pi(k) (see header).
    int t2   = tid - 8192;
    int lane = t2 & 63;
    int tile = t2 >> 6;
    int rgb  = lane & 15;
    int grp  = lane >> 4;
    uint4 v = make_uint4(0,0,0,0);
    if (rgb < 3) {
      unsigned short b[8];
      #pragma unroll
      for (int j = 0; j < 8; ++j) {
        int sig = 4*grp + (j & 3) + ((j >> 2) ? 16 : 0);   // pi(grp*8+j)
        b[j] = bfbits(cols[(tile*32 + sig)*3 + rgb]);
      }
      v = make_uint4(pkb(b[0],b[1]), pkb(b[2],b[3]), pkb(b[4],b[5]), pkb(b[6],b[7]));
    }
    ws[8192 + t2] = v;
  }
}

// Build the P (monomial) q-MFMA B-fragment for one pixel.
__device__ inline bf16x8 make_pf(float2 p, int grp) {
  float mono[6] = {p.x*p.x, p.x*p.y, p.y*p.y, p.x, p.y, 1.0f};
  unsigned short ph[6], pl[6];
  #pragma unroll
  for (int i = 0; i < 6; ++i) {
    ph[i] = bfbits(mono[i]);
    pl[i] = bfbits(mono[i] - bf2f(ph[i]));
  }
  uint4 v = make_uint4(0,0,0,0);
  if (grp == 0)      v = make_uint4(pkb(ph[0],ph[1]), pkb(ph[2],ph[3]), pkb(ph[4],ph[5]), pkb(ph[0],ph[1]));
  else if (grp == 1) v = make_uint4(pkb(ph[2],ph[3]), pkb(ph[4],ph[5]), pkb(pl[0],pl[1]), pkb(pl[2],pl[3]));
  else if (grp == 2) v = make_uint4(pkb(pl[4],pl[5]), pkb(pl[0],pl[1]), pkb(pl[2],pl[3]), pkb(pl[4],pl[5]));
  return as_bf(v);
}

// ---------------------------------------------------------------------------
// Render: 1024 blocks x 512 threads (8 waves); block = (pixblk 0-511,
// gauss-half). 16 pixels/wave. 4 blocks/CU = 32 waves/CU = 8 waves/SIMD.
// GQ staged via global_load_lds (16B width) into a 2x16KB LDS ping-pong —
// zero staging VGPRs. cols fragments loaded per step (L1-resident).
// Halves accumulate via f32 atomics after async memset.
// ---------------------------------------------------------------------------
__global__ __launch_bounds__(512, 8) void render_kernel(
    const float2* __restrict__ x, const uint4* __restrict__ ws,
    float* __restrict__ out) {
  __shared__ uint4 smem[2048];                  // 32 KB: 2 x 16KB GQ buffers
  const uint4* gq  = ws;                        // 8192 uint4
  const uint4* pvc = ws + 8192;                 // 4096 uint4

  int tid  = threadIdx.x;
  int lane = tid & 63;
  int c    = lane & 15, grp = lane >> 4;
  int wave = tid >> 6;
  int pixblk = blockIdx.x & 511;
  int half   = blockIdx.x >> 9;                 // gaussian half
  int cbase  = half * 4;                        // first 256-gauss chunk
  int wpix = pixblk * 128 + wave * 16;

  bf16x8 pf = make_pf(x[wpix + c], grp);

  f32x4 acc  = {0.f, 0.f, 0.f, 0.f};
  const f32x4 zero = {0.f, 0.f, 0.f, 0.f};

  // Direct global->LDS DMA staging (m97 pattern): linear dest, per-lane 16B.
  // smem[dst + tid] <- gq[src + tid], 1024 uint4 per chunk in 2 calls.
#define STAGE(DSTBUF, CHK) do {                                               \
    __builtin_amdgcn_global_load_lds(                                         \
      (const __attribute__((address_space(1))) void*)(gq + (CHK)*1024 + tid), \
      (__attribute__((address_space(3))) void*)(&smem[(DSTBUF)*1024 + tid]),  \
      16, 0, 0);                                                              \
    __builtin_amdgcn_global_load_lds(                                         \
      (const __attribute__((address_space(1))) void*)(gq + (CHK)*1024 + 512 + tid), \
      (__attribute__((address_space(3))) void*)(&smem[(DSTBUF)*1024 + 512 + tid]),  \
      16, 0, 0);                                                              \
  } while (0)

  STAGE(0, cbase);
  __syncthreads();                         // vmcnt drain: buf0 ready
  #pragma unroll
  for (int chk = 0; chk < 4; ++chk) {
    int buf = chk & 1;
    if (chk < 3) STAGE(buf ^ 1, cbase + chk + 1);   // async prefetch
    #pragma unroll
    for (int pr = 0; pr < 8; ++pr) {       // 8 x 32 gaussians
      uint4 ga = smem[buf*1024 + (2*pr+0)*64 + lane];
      uint4 gb = smem[buf*1024 + (2*pr+1)*64 + lane];
      uint4 cf = pvc[(cbase+chk)*512 + pr*64 + lane];   // L1-resident
      // swapped QK^T: D[gauss][pix] (row=gauss=grp*4+reg, col=pix=c)
      f32x4 q0 = __builtin_amdgcn_mfma_f32_16x16x32_bf16(as_bf(ga), pf, zero, 0, 0, 0);
      f32x4 q1 = __builtin_amdgcn_mfma_f32_16x16x32_bf16(as_bf(gb), pf, zero, 0, 0, 0);
      unsigned w0 = pk2f(__builtin_amdgcn_exp2f(q0[0]), __builtin_amdgcn_exp2f(q0[1]));
      unsigned w1 = pk2f(__builtin_amdgcn_exp2f(q0[2]), __builtin_amdgcn_exp2f(q0[3]));
      unsigned w2 = pk2f(__builtin_amdgcn_exp2f(q1[0]), __builtin_amdgcn_exp2f(q1[1]));
      unsigned w3 = pk2f(__builtin_amdgcn_exp2f(q1[2]), __builtin_amdgcn_exp2f(q1[3]));
      uint4 wf = make_uint4(w0, w1, w2, w3);
      // PV: D2[rgb][pix] += colsT(pi) * w   (row=rgb=grp*4+reg, col=pix=c)
      acc = __builtin_amdgcn_mfma_f32_16x16x32_bf16(as_bf(cf), as_bf(wf), acc, 0, 0, 0);
    }
    __syncthreads();                       // drains prefetch: next buf ready
  }
#undef STAGE

  // D2 rows 0..2 = rgb live in grp==0 lanes (regs 0..2); rows 3..15 zero.
  if (grp == 0) {
    int pix = wpix + c;
    unsafeAtomicAdd(&out[pix*3 + 0], acc[0]);
    unsafeAtomicAdd(&out[pix*3 + 1], acc[1]);
    unsafeAtomicAdd(&out[pix*3 + 2], acc[2]);
  }
}

extern "C" void kernel_launch(void* const* d_in, const int* in_sizes, int n_in,
                              void* d_out, int out_size, void* d_ws, size_t ws_size,
                              hipStream_t stream) {
  const float* x    = (const float*)d_in[0];   // [N_PIX, 2]
  const float* mus  = (const float*)d_in[1];   // [N_GAUSS, 2]
  const float* covs = (const float*)d_in[2];   // [N_GAUSS, 2, 2]
  const float* cols = (const float*)d_in[3];   // [N_GAUSS, 3]
  float* out = (float*)d_out;                  // [N_PIX, 3]
  uint4* ws  = (uint4*)d_ws;                   // 192 KB of fragments

  // halves accumulate atomically -> zero the poisoned output first
  hipMemsetAsync(out, 0, (size_t)out_size * sizeof(float), stream);

  prep_kernel<<<48, 256, 0, stream>>>(mus, covs, cols, ws);
  render_kernel<<<1024, 512, 0, stream>>>((const float2*)x, ws, out);
}